// Round 15
// baseline (465.669 us; speedup 1.0000x reference)
//
#include <hip/hip_runtime.h>

// LSTM decoder: B=1024, S=256, H=128, O=7, T=512
// gates = h @ (W_ih+W_hh).T + (b_ih+b_hh); c'=sig(f)c+sig(i)tanh(g);
// h'=sig(o)tanh(c'); pred = h' @ W_out.T + b_out
//
// Round 15 = round 11 (RB=2, 512 blocks x 512 thr, 32-slot ring, batched
// pred, bias-LDS, JIT A-frags) + the missing piece for 2 blocks/CU:
// wfrag PINNED INTO AGPRs via "a"-constrained no-op asm. Rounds 9/11
// spilled not on total regs (~110 <= 128) but on the compiler's arch/AGPR
// PARTITION (arch=64 left only 64 AGPR for wfrag+acc=80 -> 16 spilled).
// gfx950 MFMA A/B operands accept AGPR (unified file), so pinning wfrag
// to the a-side costs nothing per step and frees the arch side (~45 regs
// needed <= 48). waves_per_eu(4,4) -> cap 128 -> 4 waves/SIMD from TWO
// independent anti-phase blocks -> MFMA and VALU phases of the two blocks
// overlap (m114) instead of serializing (the ~800cyc/step round-14 loss).

#define HH   128
#define SSEQ 256
#define TT   512
#define OO   7
#define RB   2
#define HSTR 144          // ring row stride in shorts (288B = 8-bank skew)
#define RING 32
#define SLOT (RB * HSTR)  // shorts per ring slot

typedef __attribute__((ext_vector_type(8))) short short8;
typedef __attribute__((ext_vector_type(4))) float f32x4;

__device__ __forceinline__ unsigned short f2bf(float x) {
    union { float f; unsigned u; } v; v.f = x;
    return (unsigned short)((v.u + 0x7FFF + ((v.u >> 16) & 1)) >> 16); // RNE
}
__device__ __forceinline__ float sigmoidf_(float x) {
    return __builtin_amdgcn_rcpf(1.f + __expf(-x));
}
__device__ __forceinline__ float tanhf_(float x) {
    return 1.f - 2.f * __builtin_amdgcn_rcpf(__expf(2.f * x) + 1.f);
}

__global__ void __launch_bounds__(512)
__attribute__((amdgpu_waves_per_eu(4, 4)))
lstm_decoder_kernel(const float* __restrict__ ctx,
                    const float* __restrict__ Wih,
                    const float* __restrict__ Whh,
                    const float* __restrict__ bih,
                    const float* __restrict__ bhh,
                    const float* __restrict__ Wout,
                    const float* __restrict__ bout,
                    float* __restrict__ out) {
    // h ring: slot t&31 holds h_t (bf16, RB rows padded to HSTR)
    __shared__ __align__(16) unsigned short h_ring[RING * SLOT];   // 18 KB
    // W_out B-fragments, lane-indexed (conflict-free): [kt][lane][8]
    __shared__ __align__(16) unsigned short wo_frag[4][64][8];     // 4 KB
    // folded gate biases per h-column: [col][i,f,g,o]
    __shared__ __align__(16) float bias_lds[HH][4];                // 2 KB
    __shared__ float bout_lds[16];

    const int tid  = threadIdx.x;
    const int lane = tid & 63;
    const int wave = tid >> 6;
    const int rowBase = blockIdx.x * RB;

    const int lo  = lane & 15;
    const int hi  = lane >> 4;       // 0..3
    const int col = wave * 16 + lo;  // this lane's gate/h column (0..127)
    const int arw = lo & 1;          // A-tile real row (2 rows replicated to 16)
    const int erow = hi & 1;         // elementwise row (dup across hi pairs)

    // W fragments (B-operand): wave w, gate g -> n = g*128 + w*16 + lo,
    // lane holds W[n][k0..k0+7], k0 = kt*32 + hi*8. PINNED TO AGPRs below.
    short8 wfrag[4][4];
#pragma unroll
    for (int g = 0; g < 4; ++g) {
        const int n = g * HH + wave * 16 + lo;
#pragma unroll
        for (int kt = 0; kt < 4; ++kt) {
            const int k0 = kt * 32 + hi * 8;
            const float* p1 = Wih + (size_t)n * HH + k0;
            const float* p2 = Whh + (size_t)n * HH + k0;
            short8 w;
#pragma unroll
            for (int j = 0; j < 8; ++j) w[j] = (short)f2bf(p1[j] + p2[j]);
            wfrag[g][kt] = w;
        }
    }
    // Pin the 64 weight registers to the AGPR side of the unified file.
    // MFMA B-operand reads AGPR directly (gfx950) -> zero per-step cost,
    // and the arch-VGPR side shrinks to the ~45 regs the loop body needs.
#pragma unroll
    for (int g = 0; g < 4; ++g)
#pragma unroll
        for (int kt = 0; kt < 4; ++kt)
            asm volatile("" : "+a"(wfrag[g][kt]));

    // folded biases -> LDS (threads 0..127, one column each)
    if (tid < HH) {
#pragma unroll
        for (int g = 0; g < 4; ++g)
            bias_lds[tid][g] = bih[g * HH + tid] + bhh[g * HH + tid];
    }
    if (tid < 16) bout_lds[tid] = (tid < OO) ? bout[tid] : 0.f;

    // W_out B-fragments into LDS (wave 1 to spread setup work)
    if (wave == 1) {
#pragma unroll
        for (int kt = 0; kt < 4; ++kt) {
            const int k0 = kt * 32 + hi * 8;
            short8 w;
#pragma unroll
            for (int j = 0; j < 8; ++j)
                w[j] = (lo < OO) ? (short)f2bf(Wout[(size_t)lo * HH + k0 + j]) : (short)0;
            *(short8*)&wo_frag[kt][lane][0] = w;
        }
    }

    // h0 = context_seq[:, S-1, :] -> ring slot 0
    if (hi < RB) {
        const float v = ctx[(size_t)(rowBase + hi) * SSEQ * HH + (size_t)(SSEQ - 1) * HH + col];
        h_ring[hi * HSTR + col] = f2bf(v);
    }
    float c_st = 0.f;   // cell state for (row erow, col); dup across hi pairs
    __syncthreads();

    for (int it = 0; it <= TT; ++it) {
        // ---- batched pred phase every 32 steps: preds for s = it-32..it-1.
        // Ring: slot 0 = h_it (s=it-1), slot q>=1 = h_{it-32+q} (s=it-33+q).
        // 64 pred rows (32 slots x 2 batch rows) = 4 full-M tiles, waves 0..3.
        if (it >= 32 && (it & 31) == 0) {
            if (wave < 4) {
                // A row (within tile) = lo -> rho = 16*wave + lo
                const int abase = (8 * wave + (lo >> 1)) * SLOT + (lo & 1) * HSTR + hi * 8;
                const float bp = bout_lds[lo];
                f32x4 accp = {bp, bp, bp, bp};
#pragma unroll
                for (int kt = 0; kt < 4; ++kt) {
                    const short8 a  = *(const short8*)&h_ring[abase + kt * 32];
                    const short8 wp = *(const short8*)&wo_frag[kt][lane][0];
                    accp = __builtin_amdgcn_mfma_f32_16x16x32_bf16(a, wp, accp, 0, 0, 0);
                }
                // C: col=lo (output col), row=4*hi+r -> rho=16*wave+4*hi+r
                if (lo < OO) {
#pragma unroll
                    for (int r = 0; r < 4; ++r) {
                        const int q  = 8 * wave + 2 * hi + (r >> 1);  // rho>>1
                        const int br = r & 1;
                        const int s  = q ? (it - 33 + q) : (it - 1);
                        out[(size_t)(rowBase + br) * TT * OO + (size_t)s * OO + lo] = accp[r];
                    }
                }
            }
            __syncthreads();   // pred reads done before slots get overwritten
        }

        if (it == TT) break;

        // ---- LSTM step: h_it (slot it&31) -> h_{it+1} ----
        // JIT A-fragments: one short8 live + one prefetch (8 arch regs)
        const int abase = (it & 31) * SLOT + arw * HSTR + hi * 8;
        short8 a_cur = *(const short8*)&h_ring[abase];
        f32x4 acc0 = {0.f, 0.f, 0.f, 0.f};
        f32x4 acc1 = {0.f, 0.f, 0.f, 0.f};
        f32x4 acc2 = {0.f, 0.f, 0.f, 0.f};
        f32x4 acc3 = {0.f, 0.f, 0.f, 0.f};
#pragma unroll
        for (int kt = 0; kt < 4; ++kt) {
            short8 a_nxt;
            if (kt < 3) a_nxt = *(const short8*)&h_ring[abase + (kt + 1) * 32];
            acc0 = __builtin_amdgcn_mfma_f32_16x16x32_bf16(a_cur, wfrag[0][kt], acc0, 0, 0, 0);
            acc1 = __builtin_amdgcn_mfma_f32_16x16x32_bf16(a_cur, wfrag[1][kt], acc1, 0, 0, 0);
            acc2 = __builtin_amdgcn_mfma_f32_16x16x32_bf16(a_cur, wfrag[2][kt], acc2, 0, 0, 0);
            acc3 = __builtin_amdgcn_mfma_f32_16x16x32_bf16(a_cur, wfrag[3][kt], acc3, 0, 0, 0);
            if (kt < 3) a_cur = a_nxt;
        }

        // C row = 4*hi + reg; A row m holds real row m&1 -> reg r at ANY hi is
        // the gate for real row r (r<RB). Select reg r = erow in-register.
        const float gi = erow ? acc0[1] : acc0[0];
        const float gf = erow ? acc1[1] : acc1[0];
        const float gg = erow ? acc2[1] : acc2[0];
        const float go = erow ? acc3[1] : acc3[0];

        const f32x4 b4 = *(const f32x4*)&bias_lds[col][0];
        const float si_ = sigmoidf_(gi + b4[0]);
        const float sf_ = sigmoidf_(gf + b4[1]);
        const float tg  = tanhf_(gg + b4[2]);
        const float so_ = sigmoidf_(go + b4[3]);
        c_st = __builtin_fmaf(sf_, c_st, si_ * tg);
        const float hnew = so_ * tanhf_(c_st);

        if (hi < RB)
            h_ring[((it + 1) & 31) * SLOT + hi * HSTR + col] = f2bf(hnew);
        __syncthreads();
    }
}

extern "C" void kernel_launch(void* const* d_in, const int* in_sizes, int n_in,
                              void* d_out, int out_size, void* d_ws, size_t ws_size,
                              hipStream_t stream) {
    const float* ctx  = (const float*)d_in[0];
    const float* Wih  = (const float*)d_in[1];
    const float* Whh  = (const float*)d_in[2];
    const float* bih  = (const float*)d_in[3];
    const float* bhh  = (const float*)d_in[4];
    const float* Wout = (const float*)d_in[5];
    const float* bout = (const float*)d_in[6];
    float* out = (float*)d_out;

    lstm_decoder_kernel<<<dim3(1024 / RB), dim3(512), 0, stream>>>(
        ctx, Wih, Whh, bih, bhh, Wout, bout, out);
}

// Round 16
// 345.847 us; speedup vs baseline: 1.3465x; 1.3465x over previous
//
#include <hip/hip_runtime.h>

// LSTM decoder: B=1024, S=256, H=128, O=7, T=512
// gates = h @ (W_ih+W_hh).T + (b_ih+b_hh); c'=sig(f)c+sig(i)tanh(g);
// h'=sig(o)tanh(c'); pred = h' @ W_out.T + b_out
//
// Round 16 = round 14 (best, 314us: 256 blocks x 512 thr, RB=4, 32-slot
// ring, batched pred, SB-pinned MFMA/VALU interleave) + micro-levers:
//  - s_setprio stagger: waves 4..7 raise prio over the MFMA section ->
//    burst-FIFO instead of round-robin on the SIMD's MFMA pipe, so the
//    winning wave's eltwise overlaps the losing wave's MFMA tail
//  - wfrag pinned to AGPRs (proven no-spill in r15) at (512,2)
//  - loop-invariant bias f32x4 passed directly as C-input of each gate's
//    first MFMA (deletes 16 v_mov/step)
//  - v_cvt_pk_bf16_f32 for the h-store convert
// Closed axes (measured): 2 blocks/CU in any form (r2/3/6/9/10/11/12/15),
// RB<4 (M-waste doubles both pipes, r15), packed-M 64-block (fills 1/4 of
// chip), per-step pred straggler (r8), bank conflicts (0 since r8).

#define HH   128
#define SSEQ 256
#define TT   512
#define OO   7
#define RB   4
#define HSTR 144          // ring row stride in shorts (288B = 8-bank skew)
#define RING 32
#define SLOT (RB * HSTR)  // shorts per ring slot

typedef __attribute__((ext_vector_type(8))) short short8;
typedef __attribute__((ext_vector_type(4))) float f32x4;

#define SB() __builtin_amdgcn_sched_barrier(0)

__device__ __forceinline__ unsigned short f2bf(float x) {
    union { float f; unsigned u; } v; v.f = x;
    return (unsigned short)((v.u + 0x7FFF + ((v.u >> 16) & 1)) >> 16); // RNE
}
__device__ __forceinline__ float sigmoidf_(float x) {
    return __builtin_amdgcn_rcpf(1.f + __expf(-x));
}
__device__ __forceinline__ float tanhf_(float x) {
    return 1.f - 2.f * __builtin_amdgcn_rcpf(__expf(2.f * x) + 1.f);
}

__global__ void __launch_bounds__(512, 2)
lstm_decoder_kernel(const float* __restrict__ ctx,
                    const float* __restrict__ Wih,
                    const float* __restrict__ Whh,
                    const float* __restrict__ bih,
                    const float* __restrict__ bhh,
                    const float* __restrict__ Wout,
                    const float* __restrict__ bout,
                    float* __restrict__ out) {
    // h ring: slot t&31 holds h_t (bf16), rows padded to HSTR
    __shared__ __align__(16) unsigned short h_ring[RING * SLOT];   // 36 KB
    // W_out B-fragments, lane-indexed (conflict-free): [kt][lane][8]
    __shared__ __align__(16) unsigned short wo_frag[4][64][8];     // 4 KB

    const int tid  = threadIdx.x;
    const int lane = tid & 63;
    const int wave = tid >> 6;
    const int rowBase = blockIdx.x * RB;

    const int lo  = lane & 15;
    const int hi  = lane >> 4;       // 0..3: this lane's batch row AND k-slice
    const int col = wave * 16 + lo;  // this lane's gate/h column (0..127)
    const int arw = lo & 3;          // A-tile real row (rows replicated to 16)

    // folded biases for this lane's column — held as loop-invariant f32x4,
    // consumed directly as the C operand of each gate's first MFMA
    const float bi  = bih[col]          + bhh[col];
    const float bf_ = bih[HH + col]     + bhh[HH + col];
    const float bg  = bih[2 * HH + col] + bhh[2 * HH + col];
    const float bo  = bih[3 * HH + col] + bhh[3 * HH + col];
    const f32x4 bi4 = {bi, bi, bi, bi};
    const f32x4 bf4 = {bf_, bf_, bf_, bf_};
    const f32x4 bg4 = {bg, bg, bg, bg};
    const f32x4 bo4 = {bo, bo, bo, bo};
    const float bo_pred = (lo < OO) ? bout[lo] : 0.f;

    // W fragments (B-operand): wave w, gate g -> n = g*128 + w*16 + lo,
    // lane holds W[n][k0..k0+7], k0 = kt*32 + hi*8. Pinned to AGPR side.
    short8 wfrag[4][4];
#pragma unroll
    for (int g = 0; g < 4; ++g) {
        const int n = g * HH + wave * 16 + lo;
#pragma unroll
        for (int kt = 0; kt < 4; ++kt) {
            const int k0 = kt * 32 + hi * 8;
            const float* p1 = Wih + (size_t)n * HH + k0;
            const float* p2 = Whh + (size_t)n * HH + k0;
            short8 w;
#pragma unroll
            for (int j = 0; j < 8; ++j) w[j] = (short)f2bf(p1[j] + p2[j]);
            wfrag[g][kt] = w;
        }
    }
#pragma unroll
    for (int g = 0; g < 4; ++g)
#pragma unroll
        for (int kt = 0; kt < 4; ++kt)
            asm volatile("" : "+a"(wfrag[g][kt]));   // pin to AGPR side

    // W_out B-fragments into LDS (wave 0): lane holds Wout[lo][kt*32+hi*8..+8]
    if (wave == 0) {
#pragma unroll
        for (int kt = 0; kt < 4; ++kt) {
            const int k0 = kt * 32 + hi * 8;
            short8 w;
#pragma unroll
            for (int j = 0; j < 8; ++j)
                w[j] = (lo < OO) ? (short)f2bf(Wout[(size_t)lo * HH + k0 + j]) : (short)0;
            *(short8*)&wo_frag[kt][lane][0] = w;
        }
    }

    // h0 = context_seq[:, S-1, :] -> ring slot 0
    {
        const float v = ctx[(size_t)(rowBase + hi) * SSEQ * HH + (size_t)(SSEQ - 1) * HH + col];
        h_ring[hi * HSTR + col] = f2bf(v);
    }
    float c_st = 0.f;   // cell state for (row hi, col)
    __syncthreads();

    const bool late = (wave & 4) != 0;   // second wave on each SIMD

    for (int it = 0; it <= TT; ++it) {
        // ---- batched pred phase: every 32 steps, preds for s = it-32..it-1.
        if (it >= 32 && (it & 31) == 0) {
            f32x4 accp = {bo_pred, bo_pred, bo_pred, bo_pred};
            const int pbase = (4 * wave + (lo >> 2)) * SLOT + (lo & 3) * HSTR + hi * 8;
#pragma unroll
            for (int kt = 0; kt < 4; ++kt) {
                const short8 a  = *(const short8*)&h_ring[pbase + kt * 32];
                const short8 wp = *(const short8*)&wo_frag[kt][lane][0];
                accp = __builtin_amdgcn_mfma_f32_16x16x32_bf16(a, wp, accp, 0, 0, 0);
            }
            if (lo < OO) {
                const int sig = 4 * wave + hi;
                const int s   = sig ? (it - 33 + sig) : (it - 1);
#pragma unroll
                for (int r = 0; r < 4; ++r)
                    out[(size_t)(rowBase + r) * TT * OO + (size_t)s * OO + lo] = accp[r];
            }
            __syncthreads();   // pred reads done before slots get overwritten
        }

        if (it == TT) break;

        // ---- LSTM step: h_it (slot it&31) -> h_{it+1} (slot (it+1)&31) ----
        const int abase = (it & 31) * SLOT + arw * HSTR + hi * 8;
        short8 afrag[4];
#pragma unroll
        for (int kt = 0; kt < 4; ++kt)
            afrag[kt] = *(const short8*)&h_ring[abase + kt * 32];

        const bool m1 = (hi == 1), m2 = (hi == 2), m3 = (hi == 3);

        // stagger: the second wave on each SIMD takes pipe priority for its
        // MFMA burst -> burst-FIFO, its eltwise overlaps the other's tail
        if (late) __builtin_amdgcn_s_setprio(1);

        // --- cluster I (bias as C-init of first MFMA) ---
        f32x4 accI = __builtin_amdgcn_mfma_f32_16x16x32_bf16(afrag[0], wfrag[0][0], bi4, 0, 0, 0);
#pragma unroll
        for (int kt = 1; kt < 4; ++kt)
            accI = __builtin_amdgcn_mfma_f32_16x16x32_bf16(afrag[kt], wfrag[0][kt], accI, 0, 0, 0);
        SB();
        // --- cluster G ---
        f32x4 accG = __builtin_amdgcn_mfma_f32_16x16x32_bf16(afrag[0], wfrag[2][0], bg4, 0, 0, 0);
#pragma unroll
        for (int kt = 1; kt < 4; ++kt)
            accG = __builtin_amdgcn_mfma_f32_16x16x32_bf16(afrag[kt], wfrag[2][kt], accG, 0, 0, 0);
        SB();
        // VALU chunk 1: sigmoid(i)
        const float gi  = m3 ? accI[3] : m2 ? accI[2] : m1 ? accI[1] : accI[0];
        const float si_ = sigmoidf_(gi);
        SB();
        // --- cluster F ---
        f32x4 accF = __builtin_amdgcn_mfma_f32_16x16x32_bf16(afrag[0], wfrag[1][0], bf4, 0, 0, 0);
#pragma unroll
        for (int kt = 1; kt < 4; ++kt)
            accF = __builtin_amdgcn_mfma_f32_16x16x32_bf16(afrag[kt], wfrag[1][kt], accF, 0, 0, 0);
        SB();
        // VALU chunk 2: tanh(g), p = si*tg
        const float gg = m3 ? accG[3] : m2 ? accG[2] : m1 ? accG[1] : accG[0];
        const float tg = tanhf_(gg);
        const float p  = si_ * tg;
        SB();
        // --- cluster O ---
        f32x4 accO = __builtin_amdgcn_mfma_f32_16x16x32_bf16(afrag[0], wfrag[3][0], bo4, 0, 0, 0);
#pragma unroll
        for (int kt = 1; kt < 4; ++kt)
            accO = __builtin_amdgcn_mfma_f32_16x16x32_bf16(afrag[kt], wfrag[3][kt], accO, 0, 0, 0);
        if (late) __builtin_amdgcn_s_setprio(0);
        SB();
        // VALU chunk 3: sigmoid(f), c update, tanh(c)
        const float gf  = m3 ? accF[3] : m2 ? accF[2] : m1 ? accF[1] : accF[0];
        const float sf_ = sigmoidf_(gf);
        c_st = __builtin_fmaf(sf_, c_st, p);
        const float tc  = tanhf_(c_st);
        SB();
        // VALU chunk 4: sigmoid(o), h, write (single-instr bf16 convert)
        const float go  = m3 ? accO[3] : m2 ? accO[2] : m1 ? accO[1] : accO[0];
        const float so_ = sigmoidf_(go);
        const float hnew = so_ * tc;

        unsigned hpk;
        asm("v_cvt_pk_bf16_f32 %0, %1, %2" : "=v"(hpk) : "v"(hnew), "v"(hnew));
        h_ring[((it + 1) & 31) * SLOT + hi * HSTR + col] = (unsigned short)hpk;
        __syncthreads();
    }
}

extern "C" void kernel_launch(void* const* d_in, const int* in_sizes, int n_in,
                              void* d_out, int out_size, void* d_ws, size_t ws_size,
                              hipStream_t stream) {
    const float* ctx  = (const float*)d_in[0];
    const float* Wih  = (const float*)d_in[1];
    const float* Whh  = (const float*)d_in[2];
    const float* bih  = (const float*)d_in[3];
    const float* bhh  = (const float*)d_in[4];
    const float* Wout = (const float*)d_in[5];
    const float* bout = (const float*)d_in[6];
    float* out = (float*)d_out;

    lstm_decoder_kernel<<<dim3(1024 / RB), dim3(512), 0, stream>>>(
        ctx, Wih, Whh, bih, bhh, Wout, bout, out);
}

// Round 17
// 228.832 us; speedup vs baseline: 2.0350x; 1.5114x over previous
//
#include <hip/hip_runtime.h>

// LSTM decoder: B=1024, S=256, H=128, O=7, T=512
// gates = h @ (W_ih+W_hh).T + (b_ih+b_hh); c'=sig(f)c+sig(i)tanh(g);
// h'=sig(o)tanh(c'); pred = h' @ W_out.T + b_out
//
// Round 17 = round 14 structure (best, 314us: 256 blocks x 512 thr, RB=4,
// 32-slot ring, batched bf16 pred every 32 steps, SB-pinned interleave)
// with the gate matmul moved to INT8 MFMA (mfma_i32_16x16x64_i8, K=64):
//  - 8 MFMAs/step instead of 16 -> MFMA pipe 620 -> ~330 cyc/SIMD/step
//  - i32 accumulate is exact; h strictly bounded (|h|<1) -> fixed x127
//    scale; W per-row symmetric scales; h0 (unbounded) -> per-row scale
//    used for step 0 only, folded into the dequant factor
//  - arw = lo>>2: C rows 4hi+r all hold real row hi -> acc[0] IS the gate,
//    all 12 cndmask selects deleted
//  - pred stays bf16 (dual-store h to i8 ring + bf16 ring) for precision
// NO AGPR pin (r16: "+a" forced v_accvgpr_read copies, +150cyc/step).

#define HH    128
#define SSEQ  256
#define TT    512
#define OO    7
#define RB    4
#define HSTR16 144            // bf16 ring row stride (shorts)
#define SLOT16 (RB * HSTR16)  // shorts per bf16 slot
#define HSTR8  160            // i8 ring row stride (bytes): rows 8-bank skew
#define SLOT8  (RB * HSTR8)   // bytes per i8 slot
#define RING  32

typedef __attribute__((ext_vector_type(8))) short short8;
typedef __attribute__((ext_vector_type(4))) float f32x4;
typedef __attribute__((ext_vector_type(4))) int   int4v;

#define SB() __builtin_amdgcn_sched_barrier(0)

__device__ __forceinline__ unsigned short f2bf(float x) {
    union { float f; unsigned u; } v; v.f = x;
    return (unsigned short)((v.u + 0x7FFF + ((v.u >> 16) & 1)) >> 16); // RNE
}
__device__ __forceinline__ float sigmoidf_(float x) {
    return __builtin_amdgcn_rcpf(1.f + __expf(-x));
}
__device__ __forceinline__ float tanhf_(float x) {
    return 1.f - 2.f * __builtin_amdgcn_rcpf(__expf(2.f * x) + 1.f);
}

__global__ void __launch_bounds__(512, 2)
lstm_decoder_kernel(const float* __restrict__ ctx,
                    const float* __restrict__ Wih,
                    const float* __restrict__ Whh,
                    const float* __restrict__ bih,
                    const float* __restrict__ bhh,
                    const float* __restrict__ Wout,
                    const float* __restrict__ bout,
                    float* __restrict__ out) {
    // dual h rings: i8 for gate MFMAs, bf16 for the batched pred phase
    __shared__ __align__(16) char            h8_ring[RING * SLOT8];     // 20 KB
    __shared__ __align__(16) unsigned short h16_ring[RING * SLOT16];    // 36 KB
    // W_out B-fragments, lane-indexed (conflict-free): [kt][lane][8]
    __shared__ __align__(16) unsigned short wo_frag[4][64][8];          // 4 KB
    __shared__ float red[8][4];   // h0 row-max reduction scratch

    const int tid  = threadIdx.x;
    const int lane = tid & 63;
    const int wave = tid >> 6;
    const int rowBase = blockIdx.x * RB;

    const int lo   = lane & 15;
    const int hi   = lane >> 4;        // 0..3: this lane's batch row AND k-slice
    const int col  = wave * 16 + lo;   // this lane's gate/h column (0..127)
    const int arw8 = lo >> 2;          // i8 A-row mapping: C rows 4hi+r -> row hi

    // folded biases for this lane's column
    const float bi  = bih[col]          + bhh[col];
    const float bf_ = bih[HH + col]     + bhh[HH + col];
    const float bg  = bih[2 * HH + col] + bhh[2 * HH + col];
    const float bo  = bih[3 * HH + col] + bhh[3 * HH + col];
    const float bo_pred = (lo < OO) ? bout[lo] : 0.f;

    // ---- int8 W fragments: gate g, row n = g*128 + wave*16 + lo.
    // Lane holds W[n][kt*64 + hi*16 .. +16] as 16 i8 (one int4v per kt).
    // Per-row symmetric scale: rowmax over all 128 k via shfl_xor(16,32).
    int4v wq[4][2];
    float scB[4];   // rowmax/(127*127): dequant factor (x mh0 at step 0)
#pragma unroll
    for (int g = 0; g < 4; ++g) {
        const int n = g * HH + wave * 16 + lo;
        float wv[32];
        float am = 0.f;
#pragma unroll
        for (int kt = 0; kt < 2; ++kt)
#pragma unroll
            for (int j = 0; j < 16; ++j) {
                const int k = kt * 64 + hi * 16 + j;
                const float w = Wih[(size_t)n * HH + k] + Whh[(size_t)n * HH + k];
                wv[kt * 16 + j] = w;
                am = fmaxf(am, fabsf(w));
            }
        am = fmaxf(am, __shfl_xor(am, 16));
        am = fmaxf(am, __shfl_xor(am, 32));
        am = fmaxf(am, 1e-20f);
        scB[g] = am * (1.f / 16129.f);
        const float inv = 127.f / am;
#pragma unroll
        for (int kt = 0; kt < 2; ++kt) {
            int4v b;
#pragma unroll
            for (int w2 = 0; w2 < 4; ++w2) {
                int word = 0;
#pragma unroll
                for (int b_ = 0; b_ < 4; ++b_) {
                    int q = (int)__builtin_rintf(wv[kt * 16 + w2 * 4 + b_] * inv);
                    q = q > 127 ? 127 : (q < -127 ? -127 : q);
                    word |= (q & 255) << (8 * b_);
                }
                b[w2] = word;
            }
            wq[g][kt] = b;
        }
    }

    // W_out bf16 B-fragments into LDS (wave 0)
    if (wave == 0) {
#pragma unroll
        for (int kt = 0; kt < 4; ++kt) {
            const int k0 = kt * 32 + hi * 8;
            short8 w;
#pragma unroll
            for (int j = 0; j < 8; ++j)
                w[j] = (lo < OO) ? (short)f2bf(Wout[(size_t)lo * HH + k0 + j]) : (short)0;
            *(short8*)&wo_frag[kt][lane][0] = w;
        }
    }

    // ---- h0 = context_seq[:, S-1, :]; per-row max for step-0 i8 scale ----
    const float v0 = ctx[(size_t)(rowBase + hi) * SSEQ * HH + (size_t)(SSEQ - 1) * HH + col];
    float am0 = fabsf(v0);
    am0 = fmaxf(am0, __shfl_xor(am0, 1));
    am0 = fmaxf(am0, __shfl_xor(am0, 2));
    am0 = fmaxf(am0, __shfl_xor(am0, 4));
    am0 = fmaxf(am0, __shfl_xor(am0, 8));
    if (lo == 0) red[wave][hi] = am0;
    __syncthreads();
    float mh0 = 1e-20f;
#pragma unroll
    for (int w2 = 0; w2 < 8; ++w2) mh0 = fmaxf(mh0, red[w2][hi]);
    // quantize h0 into ring slot 0 (both formats)
    h8_ring[hi * HSTR8 + col]   = (char)(int)__builtin_rintf(v0 * (127.f / mh0));
    h16_ring[hi * HSTR16 + col] = f2bf(v0);
    float c_st = 0.f;   // cell state for (row hi, col)
    __syncthreads();

    for (int it = 0; it <= TT; ++it) {
        // ---- batched bf16 pred phase every 32 steps (round-14 verbatim) ----
        if (it >= 32 && (it & 31) == 0) {
            f32x4 accp = {bo_pred, bo_pred, bo_pred, bo_pred};
            const int pbase = (4 * wave + (lo >> 2)) * SLOT16 + (lo & 3) * HSTR16 + hi * 8;
#pragma unroll
            for (int kt = 0; kt < 4; ++kt) {
                const short8 a  = *(const short8*)&h16_ring[pbase + kt * 32];
                const short8 wp = *(const short8*)&wo_frag[kt][lane][0];
                accp = __builtin_amdgcn_mfma_f32_16x16x32_bf16(a, wp, accp, 0, 0, 0);
            }
            if (lo < OO) {
                const int sig = 4 * wave + hi;
                const int s   = sig ? (it - 33 + sig) : (it - 1);
#pragma unroll
                for (int r = 0; r < 4; ++r)
                    out[(size_t)(rowBase + r) * TT * OO + (size_t)s * OO + lo] = accp[r];
            }
            __syncthreads();   // pred reads done before slots get overwritten
        }

        if (it == TT) break;

        // ---- LSTM step: h_it -> h_{it+1}, int8 gate matmul ----
        const int ab8 = (it & 31) * SLOT8 + arw8 * HSTR8 + hi * 16;
        const int4v a8_0 = *(const int4v*)&h8_ring[ab8];
        const int4v a8_1 = *(const int4v*)&h8_ring[ab8 + 64];

        // step-0 scale fold (h0 used per-row scale mh0 instead of 1/127... x127)
        const float fs  = (it == 0) ? mh0 : 1.f;
        const float dqI = scB[0] * fs, dqF = scB[1] * fs;
        const float dqG = scB[2] * fs, dqO = scB[3] * fs;

        int4v accI = {0, 0, 0, 0};
        int4v accG = {0, 0, 0, 0};
        int4v accF = {0, 0, 0, 0};
        int4v accO = {0, 0, 0, 0};

        // --- cluster I ---
        accI = __builtin_amdgcn_mfma_i32_16x16x64_i8(a8_0, wq[0][0], accI, 0, 0, 0);
        accI = __builtin_amdgcn_mfma_i32_16x16x64_i8(a8_1, wq[0][1], accI, 0, 0, 0);
        SB();
        // --- cluster G ---
        accG = __builtin_amdgcn_mfma_i32_16x16x64_i8(a8_0, wq[2][0], accG, 0, 0, 0);
        accG = __builtin_amdgcn_mfma_i32_16x16x64_i8(a8_1, wq[2][1], accG, 0, 0, 0);
        SB();
        // VALU chunk 1: dequant i, sigmoid(i)   (acc[0] IS row hi: no selects)
        const float gi  = __builtin_fmaf((float)accI[0], dqI, bi);
        const float si_ = sigmoidf_(gi);
        SB();
        // --- cluster F ---
        accF = __builtin_amdgcn_mfma_i32_16x16x64_i8(a8_0, wq[1][0], accF, 0, 0, 0);
        accF = __builtin_amdgcn_mfma_i32_16x16x64_i8(a8_1, wq[1][1], accF, 0, 0, 0);
        SB();
        // VALU chunk 2: tanh(g), p = si*tg
        const float gg = __builtin_fmaf((float)accG[0], dqG, bg);
        const float tg = tanhf_(gg);
        const float p  = si_ * tg;
        SB();
        // --- cluster O ---
        accO = __builtin_amdgcn_mfma_i32_16x16x64_i8(a8_0, wq[3][0], accO, 0, 0, 0);
        accO = __builtin_amdgcn_mfma_i32_16x16x64_i8(a8_1, wq[3][1], accO, 0, 0, 0);
        SB();
        // VALU chunk 3: sigmoid(f), c update, tanh(c)
        const float gf  = __builtin_fmaf((float)accF[0], dqF, bf_);
        const float sf_ = sigmoidf_(gf);
        c_st = __builtin_fmaf(sf_, c_st, p);
        const float tc  = tanhf_(c_st);
        SB();
        // VALU chunk 4: sigmoid(o), h, dual store (i8 + bf16)
        const float go  = __builtin_fmaf((float)accO[0], dqO, bo);
        const float so_ = sigmoidf_(go);
        const float hnew = so_ * tc;   // strictly in (-1,1)

        const int dst = ((it + 1) & 31);
        h8_ring[dst * SLOT8 + hi * HSTR8 + col] =
            (char)(int)__builtin_rintf(hnew * 127.f);
        unsigned hpk;
        asm("v_cvt_pk_bf16_f32 %0, %1, %2" : "=v"(hpk) : "v"(hnew), "v"(hnew));
        h16_ring[dst * SLOT16 + hi * HSTR16 + col] = (unsigned short)hpk;
        __syncthreads();
    }
}

extern "C" void kernel_launch(void* const* d_in, const int* in_sizes, int n_in,
                              void* d_out, int out_size, void* d_ws, size_t ws_size,
                              hipStream_t stream) {
    const float* ctx  = (const float*)d_in[0];
    const float* Wih  = (const float*)d_in[1];
    const float* Whh  = (const float*)d_in[2];
    const float* bih  = (const float*)d_in[3];
    const float* bhh  = (const float*)d_in[4];
    const float* Wout = (const float*)d_in[5];
    const float* bout = (const float*)d_in[6];
    float* out = (float*)d_out;

    lstm_decoder_kernel<<<dim3(1024 / RB), dim3(512), 0, stream>>>(
        ctx, Wih, Whh, bih, bhh, Wout, bout, out);
}

// Round 18
// 223.928 us; speedup vs baseline: 2.0796x; 1.0219x over previous
//
#include <hip/hip_runtime.h>

// LSTM decoder: B=1024, S=256, H=128, O=7, T=512
// gates = h @ (W_ih+W_hh).T + (b_ih+b_hh); c'=sig(f)c+sig(i)tanh(g);
// h'=sig(o)tanh(c'); pred = h' @ W_out.T + b_out
//
// Round 18 = round 17 (228.8us: int8 gate MFMAs, dual i8/bf16 h-ring,
// batched bf16 pred, SB-pinned interleave) + two clean micro-levers:
//  - s_setprio stagger STANDALONE (r16 bundled it with the AGPR-pin poison):
//    waves 4..7 take MFMA-pipe priority -> burst-FIFO; early wave's VALU
//    overlaps late wave's MFMA burst, attacking the ~450cyc stall term
//  - step-0 peel: dq factors as loop-carried regs reset once after step 0
//    (deletes 4 cndmask + 4 mul per step)

#define HH    128
#define SSEQ  256
#define TT    512
#define OO    7
#define RB    4
#define HSTR16 144            // bf16 ring row stride (shorts)
#define SLOT16 (RB * HSTR16)  // shorts per bf16 slot
#define HSTR8  160            // i8 ring row stride (bytes): rows 8-bank skew
#define SLOT8  (RB * HSTR8)   // bytes per i8 slot
#define RING  32

typedef __attribute__((ext_vector_type(8))) short short8;
typedef __attribute__((ext_vector_type(4))) float f32x4;
typedef __attribute__((ext_vector_type(4))) int   int4v;

#define SB() __builtin_amdgcn_sched_barrier(0)

__device__ __forceinline__ unsigned short f2bf(float x) {
    union { float f; unsigned u; } v; v.f = x;
    return (unsigned short)((v.u + 0x7FFF + ((v.u >> 16) & 1)) >> 16); // RNE
}
__device__ __forceinline__ float sigmoidf_(float x) {
    return __builtin_amdgcn_rcpf(1.f + __expf(-x));
}
__device__ __forceinline__ float tanhf_(float x) {
    return 1.f - 2.f * __builtin_amdgcn_rcpf(__expf(2.f * x) + 1.f);
}

__global__ void __launch_bounds__(512, 2)
lstm_decoder_kernel(const float* __restrict__ ctx,
                    const float* __restrict__ Wih,
                    const float* __restrict__ Whh,
                    const float* __restrict__ bih,
                    const float* __restrict__ bhh,
                    const float* __restrict__ Wout,
                    const float* __restrict__ bout,
                    float* __restrict__ out) {
    // dual h rings: i8 for gate MFMAs, bf16 for the batched pred phase
    __shared__ __align__(16) char            h8_ring[RING * SLOT8];     // 20 KB
    __shared__ __align__(16) unsigned short h16_ring[RING * SLOT16];    // 36 KB
    // W_out B-fragments, lane-indexed (conflict-free): [kt][lane][8]
    __shared__ __align__(16) unsigned short wo_frag[4][64][8];          // 4 KB
    __shared__ float red[8][4];   // h0 row-max reduction scratch

    const int tid  = threadIdx.x;
    const int lane = tid & 63;
    const int wave = tid >> 6;
    const int rowBase = blockIdx.x * RB;

    const int lo   = lane & 15;
    const int hi   = lane >> 4;        // 0..3: this lane's batch row AND k-slice
    const int col  = wave * 16 + lo;   // this lane's gate/h column (0..127)
    const int arw8 = lo >> 2;          // i8 A-row mapping: C rows 4hi+r -> row hi

    // folded biases for this lane's column
    const float bi  = bih[col]          + bhh[col];
    const float bf_ = bih[HH + col]     + bhh[HH + col];
    const float bg  = bih[2 * HH + col] + bhh[2 * HH + col];
    const float bo  = bih[3 * HH + col] + bhh[3 * HH + col];
    const float bo_pred = (lo < OO) ? bout[lo] : 0.f;

    // ---- int8 W fragments: gate g, row n = g*128 + wave*16 + lo.
    // Lane holds W[n][kt*64 + hi*16 .. +16] as 16 i8 (one int4v per kt).
    // Per-row symmetric scale: rowmax over all 128 k via shfl_xor(16,32).
    int4v wq[4][2];
    float scB[4];   // rowmax/(127*127): dequant factor (x mh0 at step 0)
#pragma unroll
    for (int g = 0; g < 4; ++g) {
        const int n = g * HH + wave * 16 + lo;
        float wv[32];
        float am = 0.f;
#pragma unroll
        for (int kt = 0; kt < 2; ++kt)
#pragma unroll
            for (int j = 0; j < 16; ++j) {
                const int k = kt * 64 + hi * 16 + j;
                const float w = Wih[(size_t)n * HH + k] + Whh[(size_t)n * HH + k];
                wv[kt * 16 + j] = w;
                am = fmaxf(am, fabsf(w));
            }
        am = fmaxf(am, __shfl_xor(am, 16));
        am = fmaxf(am, __shfl_xor(am, 32));
        am = fmaxf(am, 1e-20f);
        scB[g] = am * (1.f / 16129.f);
        const float inv = 127.f / am;
#pragma unroll
        for (int kt = 0; kt < 2; ++kt) {
            int4v b;
#pragma unroll
            for (int w2 = 0; w2 < 4; ++w2) {
                int word = 0;
#pragma unroll
                for (int b_ = 0; b_ < 4; ++b_) {
                    int q = (int)__builtin_rintf(wv[kt * 16 + w2 * 4 + b_] * inv);
                    q = q > 127 ? 127 : (q < -127 ? -127 : q);
                    word |= (q & 255) << (8 * b_);
                }
                b[w2] = word;
            }
            wq[g][kt] = b;
        }
    }

    // W_out bf16 B-fragments into LDS (wave 0)
    if (wave == 0) {
#pragma unroll
        for (int kt = 0; kt < 4; ++kt) {
            const int k0 = kt * 32 + hi * 8;
            short8 w;
#pragma unroll
            for (int j = 0; j < 8; ++j)
                w[j] = (lo < OO) ? (short)f2bf(Wout[(size_t)lo * HH + k0 + j]) : (short)0;
            *(short8*)&wo_frag[kt][lane][0] = w;
        }
    }

    // ---- h0 = context_seq[:, S-1, :]; per-row max for step-0 i8 scale ----
    const float v0 = ctx[(size_t)(rowBase + hi) * SSEQ * HH + (size_t)(SSEQ - 1) * HH + col];
    float am0 = fabsf(v0);
    am0 = fmaxf(am0, __shfl_xor(am0, 1));
    am0 = fmaxf(am0, __shfl_xor(am0, 2));
    am0 = fmaxf(am0, __shfl_xor(am0, 4));
    am0 = fmaxf(am0, __shfl_xor(am0, 8));
    if (lo == 0) red[wave][hi] = am0;
    __syncthreads();
    float mh0 = 1e-20f;
#pragma unroll
    for (int w2 = 0; w2 < 8; ++w2) mh0 = fmaxf(mh0, red[w2][hi]);
    // quantize h0 into ring slot 0 (both formats)
    h8_ring[hi * HSTR8 + col]   = (char)(int)__builtin_rintf(v0 * (127.f / mh0));
    h16_ring[hi * HSTR16 + col] = f2bf(v0);
    float c_st = 0.f;   // cell state for (row hi, col)
    __syncthreads();

    // loop-carried dequant factors: step 0 folds the h0 per-row scale mh0
    float dqI = scB[0] * mh0, dqF = scB[1] * mh0;
    float dqG = scB[2] * mh0, dqO = scB[3] * mh0;

    const bool late = (wave & 4) != 0;   // second wave on each SIMD

    for (int it = 0; it <= TT; ++it) {
        // ---- batched bf16 pred phase every 32 steps (round-14 verbatim) ----
        if (it >= 32 && (it & 31) == 0) {
            f32x4 accp = {bo_pred, bo_pred, bo_pred, bo_pred};
            const int pbase = (4 * wave + (lo >> 2)) * SLOT16 + (lo & 3) * HSTR16 + hi * 8;
#pragma unroll
            for (int kt = 0; kt < 4; ++kt) {
                const short8 a  = *(const short8*)&h16_ring[pbase + kt * 32];
                const short8 wp = *(const short8*)&wo_frag[kt][lane][0];
                accp = __builtin_amdgcn_mfma_f32_16x16x32_bf16(a, wp, accp, 0, 0, 0);
            }
            if (lo < OO) {
                const int sig = 4 * wave + hi;
                const int s   = sig ? (it - 33 + sig) : (it - 1);
#pragma unroll
                for (int r = 0; r < 4; ++r)
                    out[(size_t)(rowBase + r) * TT * OO + (size_t)s * OO + lo] = accp[r];
            }
            __syncthreads();   // pred reads done before slots get overwritten
        }

        if (it == TT) break;

        // ---- LSTM step: h_it -> h_{it+1}, int8 gate matmul ----
        const int ab8 = (it & 31) * SLOT8 + arw8 * HSTR8 + hi * 16;
        const int4v a8_0 = *(const int4v*)&h8_ring[ab8];
        const int4v a8_1 = *(const int4v*)&h8_ring[ab8 + 64];

        int4v accI = {0, 0, 0, 0};
        int4v accG = {0, 0, 0, 0};
        int4v accF = {0, 0, 0, 0};
        int4v accO = {0, 0, 0, 0};

        // stagger: second wave on each SIMD takes pipe priority for its burst
        if (late) __builtin_amdgcn_s_setprio(1);

        // --- cluster I ---
        accI = __builtin_amdgcn_mfma_i32_16x16x64_i8(a8_0, wq[0][0], accI, 0, 0, 0);
        accI = __builtin_amdgcn_mfma_i32_16x16x64_i8(a8_1, wq[0][1], accI, 0, 0, 0);
        SB();
        // --- cluster G ---
        accG = __builtin_amdgcn_mfma_i32_16x16x64_i8(a8_0, wq[2][0], accG, 0, 0, 0);
        accG = __builtin_amdgcn_mfma_i32_16x16x64_i8(a8_1, wq[2][1], accG, 0, 0, 0);
        SB();
        // VALU chunk 1: dequant i, sigmoid(i)   (acc[0] IS row hi: no selects)
        const float gi  = __builtin_fmaf((float)accI[0], dqI, bi);
        const float si_ = sigmoidf_(gi);
        SB();
        // --- cluster F ---
        accF = __builtin_amdgcn_mfma_i32_16x16x64_i8(a8_0, wq[1][0], accF, 0, 0, 0);
        accF = __builtin_amdgcn_mfma_i32_16x16x64_i8(a8_1, wq[1][1], accF, 0, 0, 0);
        SB();
        // VALU chunk 2: tanh(g), p = si*tg
        const float gg = __builtin_fmaf((float)accG[0], dqG, bg);
        const float tg = tanhf_(gg);
        const float p  = si_ * tg;
        SB();
        // --- cluster O ---
        accO = __builtin_amdgcn_mfma_i32_16x16x64_i8(a8_0, wq[3][0], accO, 0, 0, 0);
        accO = __builtin_amdgcn_mfma_i32_16x16x64_i8(a8_1, wq[3][1], accO, 0, 0, 0);
        if (late) __builtin_amdgcn_s_setprio(0);
        SB();
        // VALU chunk 3: sigmoid(f), c update, tanh(c)
        const float gf  = __builtin_fmaf((float)accF[0], dqF, bf_);
        const float sf_ = sigmoidf_(gf);
        c_st = __builtin_fmaf(sf_, c_st, p);
        const float tc  = tanhf_(c_st);
        SB();
        // VALU chunk 4: sigmoid(o), h, dual store (i8 + bf16)
        const float go  = __builtin_fmaf((float)accO[0], dqO, bo);
        const float so_ = sigmoidf_(go);
        const float hnew = so_ * tc;   // strictly in (-1,1)

        const int dst = ((it + 1) & 31);
        h8_ring[dst * SLOT8 + hi * HSTR8 + col] =
            (char)(int)__builtin_rintf(hnew * 127.f);
        unsigned hpk;
        asm("v_cvt_pk_bf16_f32 %0, %1, %2" : "=v"(hpk) : "v"(hnew), "v"(hnew));
        h16_ring[dst * SLOT16 + hi * HSTR16 + col] = (unsigned short)hpk;

        // step-0 peel: drop the mh0 fold after the first iteration
        if (it == 0) {
            dqI = scB[0]; dqF = scB[1]; dqG = scB[2]; dqO = scB[3];
        }
        __syncthreads();
    }
}

extern "C" void kernel_launch(void* const* d_in, const int* in_sizes, int n_in,
                              void* d_out, int out_size, void* d_ws, size_t ws_size,
                              hipStream_t stream) {
    const float* ctx  = (const float*)d_in[0];
    const float* Wih  = (const float*)d_in[1];
    const float* Whh  = (const float*)d_in[2];
    const float* bih  = (const float*)d_in[3];
    const float* bhh  = (const float*)d_in[4];
    const float* Wout = (const float*)d_in[5];
    const float* bout = (const float*)d_in[6];
    float* out = (float*)d_out;

    lstm_decoder_kernel<<<dim3(1024 / RB), dim3(512), 0, stream>>>(
        ctx, Wih, Whh, bih, bhh, Wout, bout, out);
}

// Round 19
// 214.815 us; speedup vs baseline: 2.1678x; 1.0424x over previous
//
#include <hip/hip_runtime.h>

// LSTM decoder: B=1024, S=256, H=128, O=7, T=512
// gates = h @ (W_ih+W_hh).T + (b_ih+b_hh); c'=sig(f)c+sig(i)tanh(g);
// h'=sig(o)tanh(c'); pred = h' @ W_out.T + b_out
//
// Round 19 = round 18 (223.9us: int8 gate MFMAs, dual i8/bf16 ring, batched
// bf16 pred, SB interleave, setprio stagger, step-0 peel) + critical-path
// shaves:
//  - exp2 folding: -log2e folded into sigmoid dequant/bias constants,
//    2log2e into tanh(g)'s -> 4 v_mul deleted from the serial gate->trans
//    chains (latency AND issue)
//  - SB between tail chunks 3/4 dropped: sig(f)/c/tanh(c) and sig(o) are
//    independent until hnew -> scheduler interleaves the tail

#define HH    128
#define SSEQ  256
#define TT    512
#define OO    7
#define RB    4
#define HSTR16 144            // bf16 ring row stride (shorts)
#define SLOT16 (RB * HSTR16)  // shorts per bf16 slot
#define HSTR8  160            // i8 ring row stride (bytes): rows 8-bank skew
#define SLOT8  (RB * HSTR8)   // bytes per i8 slot
#define RING  32
#define L2E   1.44269504f

typedef __attribute__((ext_vector_type(8))) short short8;
typedef __attribute__((ext_vector_type(4))) float f32x4;
typedef __attribute__((ext_vector_type(4))) int   int4v;

#define SB() __builtin_amdgcn_sched_barrier(0)

__device__ __forceinline__ unsigned short f2bf(float x) {
    union { float f; unsigned u; } v; v.f = x;
    return (unsigned short)((v.u + 0x7FFF + ((v.u >> 16) & 1)) >> 16); // RNE
}
// sigmoid with pre-scaled argument: expects u = -x*log2e
__device__ __forceinline__ float sigm_pre(float u) {
    return __builtin_amdgcn_rcpf(1.f + __builtin_amdgcn_exp2f(u));
}
// tanh with pre-scaled argument: expects v = x*2*log2e
__device__ __forceinline__ float tanh_pre(float v) {
    const float r = __builtin_amdgcn_rcpf(__builtin_amdgcn_exp2f(v) + 1.f);
    return __builtin_fmaf(-2.f, r, 1.f);
}

__global__ void __launch_bounds__(512, 2)
lstm_decoder_kernel(const float* __restrict__ ctx,
                    const float* __restrict__ Wih,
                    const float* __restrict__ Whh,
                    const float* __restrict__ bih,
                    const float* __restrict__ bhh,
                    const float* __restrict__ Wout,
                    const float* __restrict__ bout,
                    float* __restrict__ out) {
    // dual h rings: i8 for gate MFMAs, bf16 for the batched pred phase
    __shared__ __align__(16) char            h8_ring[RING * SLOT8];     // 20 KB
    __shared__ __align__(16) unsigned short h16_ring[RING * SLOT16];    // 36 KB
    // W_out B-fragments, lane-indexed (conflict-free): [kt][lane][8]
    __shared__ __align__(16) unsigned short wo_frag[4][64][8];          // 4 KB
    __shared__ float red[8][4];   // h0 row-max reduction scratch

    const int tid  = threadIdx.x;
    const int lane = tid & 63;
    const int wave = tid >> 6;
    const int rowBase = blockIdx.x * RB;

    const int lo   = lane & 15;
    const int hi   = lane >> 4;        // 0..3: this lane's batch row AND k-slice
    const int col  = wave * 16 + lo;   // this lane's gate/h column (0..127)
    const int arw8 = lo >> 2;          // i8 A-row mapping: C rows 4hi+r -> row hi

    // folded biases for this lane's column
    const float bi  = bih[col]          + bhh[col];
    const float bf_ = bih[HH + col]     + bhh[HH + col];
    const float bg  = bih[2 * HH + col] + bhh[2 * HH + col];
    const float bo  = bih[3 * HH + col] + bhh[3 * HH + col];
    const float bo_pred = (lo < OO) ? bout[lo] : 0.f;

    // ---- int8 W fragments: gate g, row n = g*128 + wave*16 + lo.
    // Lane holds W[n][kt*64 + hi*16 .. +16] as 16 i8 (one int4v per kt).
    // Per-row symmetric scale: rowmax over all 128 k via shfl_xor(16,32).
    int4v wq[4][2];
    float scB[4];   // rowmax/(127*127): dequant factor (x mh0 at step 0)
#pragma unroll
    for (int g = 0; g < 4; ++g) {
        const int n = g * HH + wave * 16 + lo;
        float wv[32];
        float am = 0.f;
#pragma unroll
        for (int kt = 0; kt < 2; ++kt)
#pragma unroll
            for (int j = 0; j < 16; ++j) {
                const int k = kt * 64 + hi * 16 + j;
                const float w = Wih[(size_t)n * HH + k] + Whh[(size_t)n * HH + k];
                wv[kt * 16 + j] = w;
                am = fmaxf(am, fabsf(w));
            }
        am = fmaxf(am, __shfl_xor(am, 16));
        am = fmaxf(am, __shfl_xor(am, 32));
        am = fmaxf(am, 1e-20f);
        scB[g] = am * (1.f / 16129.f);
        const float inv = 127.f / am;
#pragma unroll
        for (int kt = 0; kt < 2; ++kt) {
            int4v b;
#pragma unroll
            for (int w2 = 0; w2 < 4; ++w2) {
                int word = 0;
#pragma unroll
                for (int b_ = 0; b_ < 4; ++b_) {
                    int q = (int)__builtin_rintf(wv[kt * 16 + w2 * 4 + b_] * inv);
                    q = q > 127 ? 127 : (q < -127 ? -127 : q);
                    word |= (q & 255) << (8 * b_);
                }
                b[w2] = word;
            }
            wq[g][kt] = b;
        }
    }

    // W_out bf16 B-fragments into LDS (wave 0)
    if (wave == 0) {
#pragma unroll
        for (int kt = 0; kt < 4; ++kt) {
            const int k0 = kt * 32 + hi * 8;
            short8 w;
#pragma unroll
            for (int j = 0; j < 8; ++j)
                w[j] = (lo < OO) ? (short)f2bf(Wout[(size_t)lo * HH + k0 + j]) : (short)0;
            *(short8*)&wo_frag[kt][lane][0] = w;
        }
    }

    // ---- h0 = context_seq[:, S-1, :]; per-row max for step-0 i8 scale ----
    const float v0 = ctx[(size_t)(rowBase + hi) * SSEQ * HH + (size_t)(SSEQ - 1) * HH + col];
    float am0 = fabsf(v0);
    am0 = fmaxf(am0, __shfl_xor(am0, 1));
    am0 = fmaxf(am0, __shfl_xor(am0, 2));
    am0 = fmaxf(am0, __shfl_xor(am0, 4));
    am0 = fmaxf(am0, __shfl_xor(am0, 8));
    if (lo == 0) red[wave][hi] = am0;
    __syncthreads();
    float mh0 = 1e-20f;
#pragma unroll
    for (int w2 = 0; w2 < 8; ++w2) mh0 = fmaxf(mh0, red[w2][hi]);
    // quantize h0 into ring slot 0 (both formats)
    h8_ring[hi * HSTR8 + col]   = (char)(int)__builtin_rintf(v0 * (127.f / mh0));
    h16_ring[hi * HSTR16 + col] = f2bf(v0);
    float c_st = 0.f;   // cell state for (row hi, col)
    __syncthreads();

    // pre-scaled loop-carried dequant/bias constants (exp2-domain):
    //   sigmoid gates (i,f,o): u = fma(acc, -dq*L2E, -b*L2E); sig = sigm_pre(u)
    //   tanh gate (g):         v = fma(acc, dq*2L2E, b*2L2E); tg = tanh_pre(v)
    // step 0 folds the h0 per-row scale mh0 into dq.
    float dqI = -scB[0] * mh0 * L2E, dqF = -scB[1] * mh0 * L2E;
    float dqG =  scB[2] * mh0 * 2.f * L2E, dqO = -scB[3] * mh0 * L2E;
    const float biS = -bi * L2E, bfS = -bf_ * L2E;
    const float bgS = bg * 2.f * L2E, boS = -bo * L2E;

    const bool late = (wave & 4) != 0;   // second wave on each SIMD

    for (int it = 0; it <= TT; ++it) {
        // ---- batched bf16 pred phase every 32 steps (round-14 verbatim) ----
        if (it >= 32 && (it & 31) == 0) {
            f32x4 accp = {bo_pred, bo_pred, bo_pred, bo_pred};
            const int pbase = (4 * wave + (lo >> 2)) * SLOT16 + (lo & 3) * HSTR16 + hi * 8;
#pragma unroll
            for (int kt = 0; kt < 4; ++kt) {
                const short8 a  = *(const short8*)&h16_ring[pbase + kt * 32];
                const short8 wp = *(const short8*)&wo_frag[kt][lane][0];
                accp = __builtin_amdgcn_mfma_f32_16x16x32_bf16(a, wp, accp, 0, 0, 0);
            }
            if (lo < OO) {
                const int sig = 4 * wave + hi;
                const int s   = sig ? (it - 33 + sig) : (it - 1);
#pragma unroll
                for (int r = 0; r < 4; ++r)
                    out[(size_t)(rowBase + r) * TT * OO + (size_t)s * OO + lo] = accp[r];
            }
            __syncthreads();   // pred reads done before slots get overwritten
        }

        if (it == TT) break;

        // ---- LSTM step: h_it -> h_{it+1}, int8 gate matmul ----
        const int ab8 = (it & 31) * SLOT8 + arw8 * HSTR8 + hi * 16;
        const int4v a8_0 = *(const int4v*)&h8_ring[ab8];
        const int4v a8_1 = *(const int4v*)&h8_ring[ab8 + 64];

        int4v accI = {0, 0, 0, 0};
        int4v accG = {0, 0, 0, 0};
        int4v accF = {0, 0, 0, 0};
        int4v accO = {0, 0, 0, 0};

        // stagger: second wave on each SIMD takes pipe priority for its burst
        if (late) __builtin_amdgcn_s_setprio(1);

        // --- cluster I ---
        accI = __builtin_amdgcn_mfma_i32_16x16x64_i8(a8_0, wq[0][0], accI, 0, 0, 0);
        accI = __builtin_amdgcn_mfma_i32_16x16x64_i8(a8_1, wq[0][1], accI, 0, 0, 0);
        SB();
        // --- cluster G ---
        accG = __builtin_amdgcn_mfma_i32_16x16x64_i8(a8_0, wq[2][0], accG, 0, 0, 0);
        accG = __builtin_amdgcn_mfma_i32_16x16x64_i8(a8_1, wq[2][1], accG, 0, 0, 0);
        SB();
        // VALU chunk 1: sigmoid(i) in exp2 domain (acc[0] IS row hi)
        const float si_ = sigm_pre(__builtin_fmaf((float)accI[0], dqI, biS));
        SB();
        // --- cluster F ---
        accF = __builtin_amdgcn_mfma_i32_16x16x64_i8(a8_0, wq[1][0], accF, 0, 0, 0);
        accF = __builtin_amdgcn_mfma_i32_16x16x64_i8(a8_1, wq[1][1], accF, 0, 0, 0);
        SB();
        // VALU chunk 2: tanh(g), p = si*tg
        const float tg = tanh_pre(__builtin_fmaf((float)accG[0], dqG, bgS));
        const float p  = si_ * tg;
        SB();
        // --- cluster O ---
        accO = __builtin_amdgcn_mfma_i32_16x16x64_i8(a8_0, wq[3][0], accO, 0, 0, 0);
        accO = __builtin_amdgcn_mfma_i32_16x16x64_i8(a8_1, wq[3][1], accO, 0, 0, 0);
        if (late) __builtin_amdgcn_s_setprio(0);
        SB();
        // tail (single region: sig(f)/c/tanh(c) and sig(o) interleave freely)
        const float sf_ = sigm_pre(__builtin_fmaf((float)accF[0], dqF, bfS));
        c_st = __builtin_fmaf(sf_, c_st, p);
        const float tc  = tanh_pre(c_st * (2.f * L2E));
        const float so_ = sigm_pre(__builtin_fmaf((float)accO[0], dqO, boS));
        const float hnew = so_ * tc;   // strictly in (-1,1)

        const int dst = ((it + 1) & 31);
        h8_ring[dst * SLOT8 + hi * HSTR8 + col] =
            (char)(int)__builtin_rintf(hnew * 127.f);
        unsigned hpk;
        asm("v_cvt_pk_bf16_f32 %0, %1, %2" : "=v"(hpk) : "v"(hnew), "v"(hnew));
        h16_ring[dst * SLOT16 + hi * HSTR16 + col] = (unsigned short)hpk;

        // step-0 peel: drop the mh0 fold after the first iteration
        if (it == 0) {
            dqI = -scB[0] * L2E; dqF = -scB[1] * L2E;
            dqG =  scB[2] * 2.f * L2E; dqO = -scB[3] * L2E;
        }
        __syncthreads();
    }
}

extern "C" void kernel_launch(void* const* d_in, const int* in_sizes, int n_in,
                              void* d_out, int out_size, void* d_ws, size_t ws_size,
                              hipStream_t stream) {
    const float* ctx  = (const float*)d_in[0];
    const float* Wih  = (const float*)d_in[1];
    const float* Whh  = (const float*)d_in[2];
    const float* bih  = (const float*)d_in[3];
    const float* bhh  = (const float*)d_in[4];
    const float* Wout = (const float*)d_in[5];
    const float* bout = (const float*)d_in[6];
    float* out = (float*)d_out;

    lstm_decoder_kernel<<<dim3(1024 / RB), dim3(512), 0, stream>>>(
        ctx, Wih, Whh, bih, bhh, Wout, bout, out);
}